// Round 7
// baseline (1989.606 us; speedup 1.0000x reference)
//
#include <hip/hip_runtime.h>
#include <cstddef>

// ---------------- problem constants ----------------
constexpr int B = 8, NC1 = 64, NC2 = 32, ZD = 512;
constexpr float EPS_DEMOD_F = 1e-8f;
constexpr float EPS_BN_F = 1e-5f;
constexpr float UP_STEP = 127.0f / 255.0f;   // fp32 linspace step (matches passing r2-r5)

typedef __attribute__((ext_vector_type(8))) short s16x8;   // 8 bf16 (4 VGPRs)
typedef __attribute__((ext_vector_type(4))) float f32x4;
typedef unsigned int u32;
typedef unsigned short u16;

// ---------------- workspace layout (byte offsets), ~136 MB total ----------------
constexpr size_t PLANE = 67108864;               // NHWC bf16 plane: 8*256*256 px * 64ic * 2B
constexpr size_t OFF_Y1   = 0;                   // 512 f
constexpr size_t OFF_Y2   = 2048;
constexpr size_t OFF_STATS= 4096;                // 64 f
constexpr size_t OFF_W1H  = 8192;                // 294912 u16
constexpr size_t OFF_W1L  = OFF_W1H + 589824;
constexpr size_t OFF_W2H  = OFF_W1L + 589824;    // 147456 u16
constexpr size_t OFF_W2L  = OFF_W2H + 294912;
constexpr size_t OFF_WSH  = OFF_W2L + 294912;    // 18432 u16
constexpr size_t OFF_WSL  = OFF_WSH + 36864;
constexpr size_t OFF_PLANES = 2097152;           // 2MB aligned
// upH at OFF_PLANES, o1H at OFF_PLANES+PLANE; conv2 fp32 out aliases upH (dead by then)

// ---------------- helpers ----------------
__device__ __forceinline__ u16 f2bf(float x) {           // RNE fp32 -> bf16
    u32 u = __float_as_uint(x);
    return (u16)((u + 0x7FFFu + ((u >> 16) & 1u)) >> 16);
}
__device__ __forceinline__ float bf2f(u16 h) { return __uint_as_float(((u32)h) << 16); }

__device__ __forceinline__ float mish_f(float x) {
    if (x > 20.0f) return x;
    float e = expf(x);
    float a = 1.0f + e;
    float a2 = a * a;
    return x * (a2 - 1.0f) / (a2 + 1.0f);
}

// ---------------- kernel 1: y = z @ sw.T + sb ----------------
__global__ void style_y_kernel(const float* __restrict__ z,
                               const float* __restrict__ w1, const float* __restrict__ b1,
                               const float* __restrict__ w2, const float* __restrict__ b2,
                               float* __restrict__ y1, float* __restrict__ y2) {
    int gid = blockIdx.x * blockDim.x + threadIdx.x;
    if (gid >= 2 * B * NC1) return;
    int which = gid >> 9;
    int r = gid & 511;
    int b = r >> 6, c = r & 63;
    const float* w = which ? w2 : w1;
    const float* bias = which ? b2 : b1;
    const float* zr = z + (size_t)b * ZD;
    const float* wr = w + (size_t)c * ZD;
    float acc = 0.f;
    for (int k = 0; k < ZD; k += 4) {
        float4 zv = *reinterpret_cast<const float4*>(zr + k);
        float4 wv = *reinterpret_cast<const float4*>(wr + k);
        acc += zv.x * wv.x + zv.y * wv.y + zv.z * wv.z + zv.w * wv.w;
    }
    acc += bias[c];
    (which ? y2 : y1)[r] = acc;
}

// ---------------- kernel 2: modulate + demod + hi/lo split + MFMA-swizzle ----------------
// blocks: [0,512) conv1 (b,oc), [512,768) conv2 (b,oc), [768,800) shortcut (oc). 64 threads = ic.
// A-frag layout (16x16x32): lane = (oc&15) | (q<<4), q=(ic&31)>>3, elem e=ic&7, ck=ic>>5.
// buffer layout: [b][tap][ck][ocg][lane][8]
__global__ void modulate_kernel(const float* __restrict__ conv1_w, const float* __restrict__ conv2_w,
                                const float* __restrict__ sc_w,
                                const float* __restrict__ y1, const float* __restrict__ y2,
                                u16* __restrict__ w1h, u16* __restrict__ w1l,
                                u16* __restrict__ w2h, u16* __restrict__ w2l,
                                u16* __restrict__ wsh, u16* __restrict__ wsl) {
    int bid = blockIdx.x;
    int ic = threadIdx.x;
    const float* src; u16 *dh, *dl; int oc, OCG; float m; bool demod;
    if (bid < 512) {
        int b = bid >> 6; oc = bid & 63; OCG = 4; demod = true;
        src = conv1_w + ((size_t)oc * 64 + ic) * 9;
        m = 1.0f + y1[b * 64 + ic];
        dh = w1h + (size_t)b * 36864; dl = w1l + (size_t)b * 36864;
    } else if (bid < 768) {
        int r = bid - 512; int b = r >> 5; oc = r & 31; OCG = 2; demod = true;
        src = conv2_w + ((size_t)oc * 64 + ic) * 9;
        m = 1.0f + y2[b * 64 + ic];
        dh = w2h + (size_t)b * 18432; dl = w2l + (size_t)b * 18432;
    } else {
        oc = bid - 768; OCG = 2; demod = false;
        src = sc_w + ((size_t)oc * 64 + ic) * 9;
        m = 1.0f; dh = wsh; dl = wsl;
    }
    float wv[9], ss = 0.f;
    #pragma unroll
    for (int k = 0; k < 9; ++k) { wv[k] = src[k] * m; ss += wv[k] * wv[k]; }
    #pragma unroll
    for (int off = 1; off < 64; off <<= 1) ss += __shfl_xor(ss, off);
    float d = demod ? rsqrtf(ss + EPS_DEMOD_F) : 1.0f;
    int lane = (oc & 15) | (((ic >> 3) & 3) << 4);
    int ck = ic >> 5, ocg = oc >> 4, e = ic & 7;
    #pragma unroll
    for (int tap = 0; tap < 9; ++tap) {
        float wq = wv[tap] * d;
        u16 h = f2bf(wq);
        u16 l = f2bf(wq - bf2f(h));
        size_t idx = ((((size_t)tap * 2 + ck) * OCG + ocg) * 64 + lane) * 8 + e;
        dh[idx] = h; dl[idx] = l;
    }
}

// ---------------- kernel 3: bilinear x2 upsample -> NHWC bf16 (hi only) ----------------
// block: 16x16 output px for one b; LDS stages 10x10 input window for all 64 ic.
__global__ __launch_bounds__(256) void upsample_nhwc_kernel(const float* __restrict__ in,
                                                            u16* __restrict__ upH) {
    __shared__ float L[64 * 101];   // [ic][10*10] pitch 101 (bank spread)
    int bid = blockIdx.x;
    int txt = bid & 15, tyt = (bid >> 4) & 15, b = bid >> 8;
    int row0 = tyt << 4, col0 = txt << 4;
    int iy0 = (int)(row0 * UP_STEP);
    int ix0 = (int)(col0 * UP_STEP);
    int tid = threadIdx.x;
    for (int i = tid; i < 6400; i += 256) {
        int ic = i / 100;
        int p = i - ic * 100;
        int iy = p / 10;
        int ix = p - iy * 10;
        int gy = min(iy0 + iy, 127), gx = min(ix0 + ix, 127);
        L[ic * 101 + p] = in[(((size_t)b * 64 + ic) << 14) + (gy << 7) + gx];
    }
    __syncthreads();
    int g = tid & 7, pbase = tid >> 3;
    for (int pp = 0; pp < 8; ++pp) {
        int pl = pbase + (pp << 5);
        int py = pl >> 4, px = pl & 15;
        int gy = row0 + py, gx = col0 + px;
        float fy = gy * UP_STEP; int y0 = (int)fy; float wy = fy - (float)y0;
        float fx = gx * UP_STEP; int x0 = (int)fx; float wx = fx - (float)x0;
        int ly = (y0 - iy0) * 10, lx = x0 - ix0;
        int ly1 = ly + ((y0 < 127) ? 10 : 0);
        int lx1 = lx + (x0 < 127);
        u32 hp[4];
        #pragma unroll
        for (int e2 = 0; e2 < 4; ++e2) {
            u16 hh[2];
            #pragma unroll
            for (int h = 0; h < 2; ++h) {
                int ic = g * 8 + e2 * 2 + h;
                const float* P = &L[ic * 101];
                float v00 = P[ly + lx], v01 = P[ly + lx1];
                float v10 = P[ly1 + lx], v11 = P[ly1 + lx1];
                float r0 = v00 * (1.0f - wy) + v10 * wy;   // H first, then W (matches ref)
                float r1 = v01 * (1.0f - wy) + v11 * wy;
                float v = r0 * (1.0f - wx) + r1 * wx;
                hh[h] = f2bf(v);
            }
            hp[e2] = (u32)hh[0] | ((u32)hh[1] << 16);
        }
        size_t rb = ((((size_t)b << 16) + ((size_t)gy << 8) + gx) << 6) + g * 8;
        *reinterpret_cast<uint4*>(upH + rb) = make_uint4(hp[0], hp[1], hp[2], hp[3]);
    }
}

// ---------------- kernel 4: MFMA 3x3 conv, 16 oc per block (no spill) ----------------
// Strip: 4 rows x 64 cols output px, ONE og (16 oc) per block. 256 thr = 4 waves; wave w = row w.
// A = weights (M=16 oc, K=32ic), B = input px (N=16). D (m89): col=lane&15=px, row=(lane>>4)*4+reg=oc.
// Live state/lane: acc 16 AGPR + wfh,wfl 8 + ih[4] 16 + addr ~15 -> no scratch (r5's OCG=4 spilled).
// LDS: halo 6x66 px records, hi only; RECB=80 (64B data + 16B pad; frag reads 2-way banked = free).
template<int OGSH, bool PER_B, bool DO_MISH, bool OUT_BF16, bool STATS_>
__global__ __launch_bounds__(256) void conv_mfma16_kernel(
        const u16* __restrict__ inH,
        const u16* __restrict__ wH, const u16* __restrict__ wL,
        float* __restrict__ outF, u16* __restrict__ outH,
        float* __restrict__ stats) {
    constexpr int NOG = 1 << OGSH;
    constexpr int OC = 16 << OGSH;
    constexpr int RECB = 80;
    __shared__ __align__(16) char lds[396 * RECB];
    const int tid = threadIdx.x;
    const int lane = tid & 63, w = tid >> 6;
    const int bid = blockIdx.x;
    const int ct = bid & 3, rt = (bid >> 2) & 63;
    const int og = (bid >> 8) & (NOG - 1);
    const int b = bid >> (8 + OGSH);
    const int row0 = rt << 2, col0 = ct << 6;

    const size_t wboff = (PER_B ? (size_t)b * (9 * 2 * NOG * 512) : 0) + (size_t)lane * 8;
    const u16* wHp = wH + wboff;
    const u16* wLp = wL + wboff;

    f32x4 acc[4];
    #pragma unroll
    for (int pg = 0; pg < 4; ++pg) acc[pg] = f32x4{0.f, 0.f, 0.f, 0.f};

    for (int ck = 0; ck < 2; ++ck) {
        // stage halo (hi plane only): 396 records x 64B
        for (int j = tid; j < 396 * 4; j += 256) {
            int rec = j >> 2, g = j & 3;
            int hy = rec / 66;
            int hx = rec - hy * 66;
            int gy = row0 - 1 + hy, gx = col0 - 1 + hx;
            uint4 v = make_uint4(0, 0, 0, 0);
            if ((unsigned)gy < 256u && (unsigned)gx < 256u) {
                size_t off = ((((size_t)b << 16) + ((size_t)gy << 8) + gx) << 6) + (ck << 5) + (g << 3);
                v = *reinterpret_cast<const uint4*>(inH + off);
            }
            *reinterpret_cast<uint4*>(lds + (size_t)rec * RECB + g * 16) = v;
        }
        __syncthreads();
        #pragma unroll
        for (int kh = 0; kh < 3; ++kh)
            #pragma unroll
            for (int kw = 0; kw < 3; ++kw) {
                const int tap = kh * 3 + kw;
                const size_t wb = (size_t)(((tap * 2 + ck) * NOG) + og) * 512;
                s16x8 wfh = *reinterpret_cast<const s16x8*>(wHp + wb);
                s16x8 wfl = *reinterpret_cast<const s16x8*>(wLp + wb);
                const int recb = (w + kh) * 66 + kw + (lane & 15);
                const int qoff = (lane >> 4) << 4;
                s16x8 ih[4];
                #pragma unroll
                for (int pg = 0; pg < 4; ++pg)
                    ih[pg] = *reinterpret_cast<const s16x8*>(lds + (size_t)(recb + pg * 16) * RECB + qoff);
                #pragma unroll
                for (int pg = 0; pg < 4; ++pg) {
                    acc[pg] = __builtin_amdgcn_mfma_f32_16x16x32_bf16(wfh, ih[pg], acc[pg], 0, 0, 0);
                    acc[pg] = __builtin_amdgcn_mfma_f32_16x16x32_bf16(wfl, ih[pg], acc[pg], 0, 0, 0);
                }
            }
        __syncthreads();
    }

    // ---- epilogue ----
    const int q = lane >> 4;             // D row block -> oc sub-group
    const int cl = lane & 15;            // D col -> px
    #pragma unroll
    for (int pg = 0; pg < 4; ++pg) {
        int gx = col0 + pg * 16 + cl;
        if (OUT_BF16) {
            size_t rb = ((((size_t)b << 16) + ((size_t)(row0 + w) << 8) + gx) << 6) + og * 16 + q * 4;
            u16 hh[4];
            #pragma unroll
            for (int r = 0; r < 4; ++r) {
                float v = acc[pg][r];
                if (DO_MISH) v = mish_f(v);
                hh[r] = f2bf(v);
            }
            *reinterpret_cast<uint2*>(outH + rb) =
                make_uint2((u32)hh[0] | ((u32)hh[1] << 16), (u32)hh[2] | ((u32)hh[3] << 16));
        } else {
            #pragma unroll
            for (int r = 0; r < 4; ++r) {
                float v = acc[pg][r];
                if (DO_MISH) v = mish_f(v);
                int oc = og * 16 + q * 4 + r;
                outF[(((size_t)b * OC + oc) << 16) + ((size_t)(row0 + w) << 8) + gx] = v;
            }
        }
    }
    if (STATS_) {
        #pragma unroll
        for (int r = 0; r < 4; ++r) {
            float s = 0.f, s2 = 0.f;
            #pragma unroll
            for (int pg = 0; pg < 4; ++pg) { float v = acc[pg][r]; s += v; s2 += v * v; }
            s += __shfl_xor(s, 1); s2 += __shfl_xor(s2, 1);
            s += __shfl_xor(s, 2); s2 += __shfl_xor(s2, 2);
            s += __shfl_xor(s, 4); s2 += __shfl_xor(s2, 4);
            s += __shfl_xor(s, 8); s2 += __shfl_xor(s2, 8);
            if (cl == 0) {
                int oc = og * 16 + q * 4 + r;
                atomicAdd(&stats[2 * oc], s);
                atomicAdd(&stats[2 * oc + 1], s2);
            }
        }
    }
}

// ---------------- kernel 5: BN finalize + residual add (d_out holds sc) ----------------
__global__ void final_kernel(float* __restrict__ out, const float* __restrict__ c2,
                             const float* __restrict__ stats, const float* __restrict__ gamma,
                             const float* __restrict__ beta) {
    const int n4 = B * NC2 * 256 * 256 / 4;
    const float inv_cnt = 1.0f / (float)(B * 256 * 256);
    for (int i = blockIdx.x * blockDim.x + threadIdx.x; i < n4; i += gridDim.x * blockDim.x) {
        int c = (i >> 14) & 31;
        float mean = stats[2 * c] * inv_cnt;
        float var = stats[2 * c + 1] * inv_cnt - mean * mean;
        float g = gamma[c] * rsqrtf(var + EPS_BN_F);
        float bt = beta[c] - mean * g;     // sc conv bias cancels exactly in batch-stats BN
        float4 a = reinterpret_cast<const float4*>(c2)[i];
        float4 s = reinterpret_cast<float4*>(out)[i];
        float4 o;
        o.x = a.x + s.x * g + bt;
        o.y = a.y + s.y * g + bt;
        o.z = a.z + s.z * g + bt;
        o.w = a.w + s.w * g + bt;
        reinterpret_cast<float4*>(out)[i] = o;
    }
}

// ---------------- launch ----------------
extern "C" void kernel_launch(void* const* d_in, const int* in_sizes, int n_in,
                              void* d_out, int out_size, void* d_ws, size_t ws_size,
                              hipStream_t stream) {
    (void)in_sizes; (void)n_in; (void)out_size; (void)ws_size;
    const float* input   = (const float*)d_in[0];
    const float* z       = (const float*)d_in[1];
    const float* ws1_w   = (const float*)d_in[2];
    const float* ws1_b   = (const float*)d_in[3];
    const float* conv1_w = (const float*)d_in[4];
    const float* ws2_w   = (const float*)d_in[5];
    const float* ws2_b   = (const float*)d_in[6];
    const float* conv2_w = (const float*)d_in[7];
    const float* sc_w    = (const float*)d_in[8];
    // d_in[9] = sc_b: cancels exactly under training-mode BN
    const float* bn_gamma = (const float*)d_in[10];
    const float* bn_beta  = (const float*)d_in[11];

    char* ws = (char*)d_ws;
    float* y1    = (float*)(ws + OFF_Y1);
    float* y2    = (float*)(ws + OFF_Y2);
    float* stats = (float*)(ws + OFF_STATS);
    u16* w1h = (u16*)(ws + OFF_W1H);
    u16* w1l = (u16*)(ws + OFF_W1L);
    u16* w2h = (u16*)(ws + OFF_W2H);
    u16* w2l = (u16*)(ws + OFF_W2L);
    u16* wsh = (u16*)(ws + OFF_WSH);
    u16* wsl = (u16*)(ws + OFF_WSL);
    u16* upH = (u16*)(ws + OFF_PLANES);
    u16* o1H = (u16*)(ws + OFF_PLANES + PLANE);
    float* tmp2 = (float*)(ws + OFF_PLANES);   // conv2 fp32 out (64MB) aliases upH (dead after sc)
    float* outp = (float*)d_out;

    hipMemsetAsync(stats, 0, 2 * NC2 * sizeof(float), stream);
    style_y_kernel<<<4, 256, 0, stream>>>(z, ws1_w, ws1_b, ws2_w, ws2_b, y1, y2);
    modulate_kernel<<<800, 64, 0, stream>>>(conv1_w, conv2_w, sc_w, y1, y2, w1h, w1l, w2h, w2l, wsh, wsl);

    upsample_nhwc_kernel<<<2048, 256, 0, stream>>>(input, upH);

    // conv1: up -> o1H (NHWC bf16), mish, per-batch weights. 4(ct)x64(rt)x4(og)x8(b)=8192 blocks
    conv_mfma16_kernel<2, true, true, true, false><<<8192, 256, 0, stream>>>(
        upH, w1h, w1l, nullptr, o1H, nullptr);
    // shortcut: up -> d_out (fp32 NCHW), BN stats. 4x64x2x8=4096 blocks
    conv_mfma16_kernel<1, false, false, false, true><<<4096, 256, 0, stream>>>(
        upH, wsh, wsl, outp, nullptr, stats);
    // conv2: o1H -> tmp2 (fp32 NCHW, aliases upH), mish. 4096 blocks
    conv_mfma16_kernel<1, true, true, false, false><<<4096, 256, 0, stream>>>(
        o1H, w2h, w2l, tmp2, nullptr, nullptr);

    // out = conv2 + gamma_hat * sc + beta_hat   (in place on d_out)
    final_kernel<<<2048, 256, 0, stream>>>(outp, tmp2, stats, bn_gamma, bn_beta);
}

// Round 8
// 460.614 us; speedup vs baseline: 4.3195x; 4.3195x over previous
//
#include <hip/hip_runtime.h>
#include <cstddef>

// ---------------- problem constants ----------------
constexpr int B = 8, NC1 = 64, NC2 = 32, ZD = 512;
constexpr float EPS_DEMOD_F = 1e-8f;
constexpr float EPS_BN_F = 1e-5f;
constexpr float UP_STEP = 127.0f / 255.0f;   // fp32 linspace step (matches passing r2-r7)

typedef __attribute__((ext_vector_type(8))) short s16x8;   // 8 bf16 (4 VGPRs)
typedef __attribute__((ext_vector_type(4))) float f32x4;
typedef unsigned int u32;
typedef unsigned short u16;

// ---------------- workspace layout (byte offsets), ~136 MB total ----------------
constexpr size_t PLANE = 67108864;               // NHWC bf16 plane: 8*256*256 px * 64ic * 2B
constexpr size_t OFF_Y1   = 0;                   // 512 f
constexpr size_t OFF_Y2   = 2048;
constexpr size_t OFF_STATS= 4096;                // 64 f (reduced stats)
constexpr size_t OFF_SBUCK= 8192;                // 128 slices x 64 f = 32 KB atomic buckets
constexpr size_t OFF_W1H  = 40960;               // 294912 u16
constexpr size_t OFF_W1L  = OFF_W1H + 589824;
constexpr size_t OFF_W2H  = OFF_W1L + 589824;    // 147456 u16
constexpr size_t OFF_W2L  = OFF_W2H + 294912;
constexpr size_t OFF_WSH  = OFF_W2L + 294912;    // 18432 u16
constexpr size_t OFF_WSL  = OFF_WSH + 36864;     // ends 1884160 < 2097152
constexpr size_t OFF_PLANES = 2097152;           // 2MB aligned
// upH at OFF_PLANES, o1H at OFF_PLANES+PLANE; conv2 fp32 out aliases upH (dead by then)

// ---------------- helpers ----------------
__device__ __forceinline__ u16 f2bf(float x) {           // RNE fp32 -> bf16
    u32 u = __float_as_uint(x);
    return (u16)((u + 0x7FFFu + ((u >> 16) & 1u)) >> 16);
}
__device__ __forceinline__ float bf2f(u16 h) { return __uint_as_float(((u32)h) << 16); }

__device__ __forceinline__ float mish_f(float x) {
    if (x > 20.0f) return x;
    float e = expf(x);
    float a = 1.0f + e;
    float a2 = a * a;
    return x * (a2 - 1.0f) / (a2 + 1.0f);
}

// ---------------- kernel 1: y = z @ sw.T + sb ----------------
__global__ void style_y_kernel(const float* __restrict__ z,
                               const float* __restrict__ w1, const float* __restrict__ b1,
                               const float* __restrict__ w2, const float* __restrict__ b2,
                               float* __restrict__ y1, float* __restrict__ y2) {
    int gid = blockIdx.x * blockDim.x + threadIdx.x;
    if (gid >= 2 * B * NC1) return;
    int which = gid >> 9;
    int r = gid & 511;
    int b = r >> 6, c = r & 63;
    const float* w = which ? w2 : w1;
    const float* bias = which ? b2 : b1;
    const float* zr = z + (size_t)b * ZD;
    const float* wr = w + (size_t)c * ZD;
    float acc = 0.f;
    for (int k = 0; k < ZD; k += 4) {
        float4 zv = *reinterpret_cast<const float4*>(zr + k);
        float4 wv = *reinterpret_cast<const float4*>(wr + k);
        acc += zv.x * wv.x + zv.y * wv.y + zv.z * wv.z + zv.w * wv.w;
    }
    acc += bias[c];
    (which ? y2 : y1)[r] = acc;
}

// ---------------- kernel 2: modulate + demod + hi/lo split + MFMA-swizzle ----------------
// blocks: [0,512) conv1 (b,oc), [512,768) conv2 (b,oc), [768,800) shortcut (oc). 64 threads = ic.
// A-frag layout (16x16x32): lane = (oc&15) | (q<<4), q=(ic&31)>>3, elem e=ic&7, ck=ic>>5.
// buffer layout: [b][tap][ck][ocg][lane][8]
__global__ void modulate_kernel(const float* __restrict__ conv1_w, const float* __restrict__ conv2_w,
                                const float* __restrict__ sc_w,
                                const float* __restrict__ y1, const float* __restrict__ y2,
                                u16* __restrict__ w1h, u16* __restrict__ w1l,
                                u16* __restrict__ w2h, u16* __restrict__ w2l,
                                u16* __restrict__ wsh, u16* __restrict__ wsl) {
    int bid = blockIdx.x;
    int ic = threadIdx.x;
    const float* src; u16 *dh, *dl; int oc, OCG; float m; bool demod;
    if (bid < 512) {
        int b = bid >> 6; oc = bid & 63; OCG = 4; demod = true;
        src = conv1_w + ((size_t)oc * 64 + ic) * 9;
        m = 1.0f + y1[b * 64 + ic];
        dh = w1h + (size_t)b * 36864; dl = w1l + (size_t)b * 36864;
    } else if (bid < 768) {
        int r = bid - 512; int b = r >> 5; oc = r & 31; OCG = 2; demod = true;
        src = conv2_w + ((size_t)oc * 64 + ic) * 9;
        m = 1.0f + y2[b * 64 + ic];
        dh = w2h + (size_t)b * 18432; dl = w2l + (size_t)b * 18432;
    } else {
        oc = bid - 768; OCG = 2; demod = false;
        src = sc_w + ((size_t)oc * 64 + ic) * 9;
        m = 1.0f; dh = wsh; dl = wsl;
    }
    float wv[9], ss = 0.f;
    #pragma unroll
    for (int k = 0; k < 9; ++k) { wv[k] = src[k] * m; ss += wv[k] * wv[k]; }
    #pragma unroll
    for (int off = 1; off < 64; off <<= 1) ss += __shfl_xor(ss, off);
    float d = demod ? rsqrtf(ss + EPS_DEMOD_F) : 1.0f;
    int lane = (oc & 15) | (((ic >> 3) & 3) << 4);
    int ck = ic >> 5, ocg = oc >> 4, e = ic & 7;
    #pragma unroll
    for (int tap = 0; tap < 9; ++tap) {
        float wq = wv[tap] * d;
        u16 h = f2bf(wq);
        u16 l = f2bf(wq - bf2f(h));
        size_t idx = ((((size_t)tap * 2 + ck) * OCG + ocg) * 64 + lane) * 8 + e;
        dh[idx] = h; dl[idx] = l;
    }
}

// ---------------- kernel 3: bilinear x2 upsample -> NHWC bf16 (hi only) ----------------
// block: 16x16 output px for one b; LDS stages 10x10 input window for all 64 ic.
__global__ __launch_bounds__(256) void upsample_nhwc_kernel(const float* __restrict__ in,
                                                            u16* __restrict__ upH) {
    __shared__ float L[64 * 101];   // [ic][10*10] pitch 101 (bank spread)
    int bid = blockIdx.x;
    int txt = bid & 15, tyt = (bid >> 4) & 15, b = bid >> 8;
    int row0 = tyt << 4, col0 = txt << 4;
    int iy0 = (int)(row0 * UP_STEP);
    int ix0 = (int)(col0 * UP_STEP);
    int tid = threadIdx.x;
    for (int i = tid; i < 6400; i += 256) {
        int ic = i / 100;
        int p = i - ic * 100;
        int iy = p / 10;
        int ix = p - iy * 10;
        int gy = min(iy0 + iy, 127), gx = min(ix0 + ix, 127);
        L[ic * 101 + p] = in[(((size_t)b * 64 + ic) << 14) + (gy << 7) + gx];
    }
    __syncthreads();
    int g = tid & 7, pbase = tid >> 3;
    for (int pp = 0; pp < 8; ++pp) {
        int pl = pbase + (pp << 5);
        int py = pl >> 4, px = pl & 15;
        int gy = row0 + py, gx = col0 + px;
        float fy = gy * UP_STEP; int y0 = (int)fy; float wy = fy - (float)y0;
        float fx = gx * UP_STEP; int x0 = (int)fx; float wx = fx - (float)x0;
        int ly = (y0 - iy0) * 10, lx = x0 - ix0;
        int ly1 = ly + ((y0 < 127) ? 10 : 0);
        int lx1 = lx + (x0 < 127);
        u32 hp[4];
        #pragma unroll
        for (int e2 = 0; e2 < 4; ++e2) {
            u16 hh[2];
            #pragma unroll
            for (int h = 0; h < 2; ++h) {
                int ic = g * 8 + e2 * 2 + h;
                const float* P = &L[ic * 101];
                float v00 = P[ly + lx], v01 = P[ly + lx1];
                float v10 = P[ly1 + lx], v11 = P[ly1 + lx1];
                float r0 = v00 * (1.0f - wy) + v10 * wy;   // H first, then W (matches ref)
                float r1 = v01 * (1.0f - wy) + v11 * wy;
                float v = r0 * (1.0f - wx) + r1 * wx;
                hh[h] = f2bf(v);
            }
            hp[e2] = (u32)hh[0] | ((u32)hh[1] << 16);
        }
        size_t rb = ((((size_t)b << 16) + ((size_t)gy << 8) + gx) << 6) + g * 8;
        *reinterpret_cast<uint4*>(upH + rb) = make_uint4(hp[0], hp[1], hp[2], hp[3]);
    }
}

// ---------------- kernel 4: MFMA 3x3 conv, 16 oc per block ----------------
// Strip: 4 rows x 64 cols output px, ONE og (16 oc) per block. 256 thr = 4 waves; wave w = row w.
// A = weights (M=16 oc, K=32ic), B = input px (N=16). D (m89): col=lane&15=px, row=(lane>>4)*4+reg=oc.
// STATS: LDS cross-wave merge (reusing dead halo LDS) + sliced atomic buckets (bid&127)
//        -> 32 atomics/block over 8192 addresses (was 128/block onto 64 addresses = 2 cache
//        lines = 524K serialized RMW ~ 1.5 ms, the r5/r7 1600-us stall).
template<int OGSH, bool PER_B, bool DO_MISH, bool OUT_BF16, bool STATS_>
__global__ __launch_bounds__(256) void conv_mfma16_kernel(
        const u16* __restrict__ inH,
        const u16* __restrict__ wH, const u16* __restrict__ wL,
        float* __restrict__ outF, u16* __restrict__ outH,
        float* __restrict__ sbucket) {
    constexpr int NOG = 1 << OGSH;
    constexpr int OC = 16 << OGSH;
    constexpr int RECB = 80;
    __shared__ __align__(16) char lds[396 * RECB];
    const int tid = threadIdx.x;
    const int lane = tid & 63, w = tid >> 6;
    const int bid = blockIdx.x;
    const int ct = bid & 3, rt = (bid >> 2) & 63;
    const int og = (bid >> 8) & (NOG - 1);
    const int b = bid >> (8 + OGSH);
    const int row0 = rt << 2, col0 = ct << 6;

    const size_t wboff = (PER_B ? (size_t)b * (9 * 2 * NOG * 512) : 0) + (size_t)lane * 8;
    const u16* wHp = wH + wboff;
    const u16* wLp = wL + wboff;

    f32x4 acc[4];
    #pragma unroll
    for (int pg = 0; pg < 4; ++pg) acc[pg] = f32x4{0.f, 0.f, 0.f, 0.f};

    for (int ck = 0; ck < 2; ++ck) {
        // stage halo (hi plane only): 396 records x 64B
        for (int j = tid; j < 396 * 4; j += 256) {
            int rec = j >> 2, g = j & 3;
            int hy = rec / 66;
            int hx = rec - hy * 66;
            int gy = row0 - 1 + hy, gx = col0 - 1 + hx;
            uint4 v = make_uint4(0, 0, 0, 0);
            if ((unsigned)gy < 256u && (unsigned)gx < 256u) {
                size_t off = ((((size_t)b << 16) + ((size_t)gy << 8) + gx) << 6) + (ck << 5) + (g << 3);
                v = *reinterpret_cast<const uint4*>(inH + off);
            }
            *reinterpret_cast<uint4*>(lds + (size_t)rec * RECB + g * 16) = v;
        }
        __syncthreads();
        #pragma unroll
        for (int kh = 0; kh < 3; ++kh)
            #pragma unroll
            for (int kw = 0; kw < 3; ++kw) {
                const int tap = kh * 3 + kw;
                const size_t wb = (size_t)(((tap * 2 + ck) * NOG) + og) * 512;
                s16x8 wfh = *reinterpret_cast<const s16x8*>(wHp + wb);
                s16x8 wfl = *reinterpret_cast<const s16x8*>(wLp + wb);
                const int recb = (w + kh) * 66 + kw + (lane & 15);
                const int qoff = (lane >> 4) << 4;
                s16x8 ih[4];
                #pragma unroll
                for (int pg = 0; pg < 4; ++pg)
                    ih[pg] = *reinterpret_cast<const s16x8*>(lds + (size_t)(recb + pg * 16) * RECB + qoff);
                #pragma unroll
                for (int pg = 0; pg < 4; ++pg) {
                    acc[pg] = __builtin_amdgcn_mfma_f32_16x16x32_bf16(wfh, ih[pg], acc[pg], 0, 0, 0);
                    acc[pg] = __builtin_amdgcn_mfma_f32_16x16x32_bf16(wfl, ih[pg], acc[pg], 0, 0, 0);
                }
            }
        __syncthreads();
    }

    // ---- epilogue ----
    const int q = lane >> 4;             // D row block -> oc sub-group
    const int cl = lane & 15;            // D col -> px
    #pragma unroll
    for (int pg = 0; pg < 4; ++pg) {
        int gx = col0 + pg * 16 + cl;
        if (OUT_BF16) {
            size_t rb = ((((size_t)b << 16) + ((size_t)(row0 + w) << 8) + gx) << 6) + og * 16 + q * 4;
            u16 hh[4];
            #pragma unroll
            for (int r = 0; r < 4; ++r) {
                float v = acc[pg][r];
                if (DO_MISH) v = mish_f(v);
                hh[r] = f2bf(v);
            }
            *reinterpret_cast<uint2*>(outH + rb) =
                make_uint2((u32)hh[0] | ((u32)hh[1] << 16), (u32)hh[2] | ((u32)hh[3] << 16));
        } else {
            #pragma unroll
            for (int r = 0; r < 4; ++r) {
                float v = acc[pg][r];
                if (DO_MISH) v = mish_f(v);
                int oc = og * 16 + q * 4 + r;
                outF[(((size_t)b * OC + oc) << 16) + ((size_t)(row0 + w) << 8) + gx] = v;
            }
        }
    }
    if (STATS_) {
        // halo LDS is dead after the final barrier -> reuse as [wave][16 oc][2] merge buffer
        float* sred = reinterpret_cast<float*>(lds);
        #pragma unroll
        for (int r = 0; r < 4; ++r) {
            float s = 0.f, s2 = 0.f;
            #pragma unroll
            for (int pg = 0; pg < 4; ++pg) { float v = acc[pg][r]; s += v; s2 += v * v; }
            s += __shfl_xor(s, 1); s2 += __shfl_xor(s2, 1);
            s += __shfl_xor(s, 2); s2 += __shfl_xor(s2, 2);
            s += __shfl_xor(s, 4); s2 += __shfl_xor(s2, 4);
            s += __shfl_xor(s, 8); s2 += __shfl_xor(s2, 8);
            if (cl == 0) {
                int ol = q * 4 + r;                // 0..15
                sred[(w * 16 + ol) * 2 + 0] = s;
                sred[(w * 16 + ol) * 2 + 1] = s2;
            }
        }
        __syncthreads();
        if (tid < 32) {
            int ol = tid >> 1, which = tid & 1;
            float v = sred[(0 * 16 + ol) * 2 + which] + sred[(1 * 16 + ol) * 2 + which]
                    + sred[(2 * 16 + ol) * 2 + which] + sred[(3 * 16 + ol) * 2 + which];
            atomicAdd(&sbucket[(size_t)(bid & 127) * 64 + (og * 16 + ol) * 2 + which], v);
        }
    }
}

// ---------------- kernel 4b: fold 128 slice buckets -> stats[64] ----------------
__global__ void stats_reduce_kernel(const float* __restrict__ bucket, float* __restrict__ stats) {
    int t = threadIdx.x;     // 64 threads
    if (t >= 64) return;
    float s = 0.f;
    for (int sl = 0; sl < 128; ++sl) s += bucket[(size_t)sl * 64 + t];
    stats[t] = s;
}

// ---------------- kernel 5: BN finalize + residual add (d_out holds sc) ----------------
__global__ void final_kernel(float* __restrict__ out, const float* __restrict__ c2,
                             const float* __restrict__ stats, const float* __restrict__ gamma,
                             const float* __restrict__ beta) {
    const int n4 = B * NC2 * 256 * 256 / 4;
    const float inv_cnt = 1.0f / (float)(B * 256 * 256);
    for (int i = blockIdx.x * blockDim.x + threadIdx.x; i < n4; i += gridDim.x * blockDim.x) {
        int c = (i >> 14) & 31;
        float mean = stats[2 * c] * inv_cnt;
        float var = stats[2 * c + 1] * inv_cnt - mean * mean;
        float g = gamma[c] * rsqrtf(var + EPS_BN_F);
        float bt = beta[c] - mean * g;     // sc conv bias cancels exactly in batch-stats BN
        float4 a = reinterpret_cast<const float4*>(c2)[i];
        float4 s = reinterpret_cast<float4*>(out)[i];
        float4 o;
        o.x = a.x + s.x * g + bt;
        o.y = a.y + s.y * g + bt;
        o.z = a.z + s.z * g + bt;
        o.w = a.w + s.w * g + bt;
        reinterpret_cast<float4*>(out)[i] = o;
    }
}

// ---------------- launch ----------------
extern "C" void kernel_launch(void* const* d_in, const int* in_sizes, int n_in,
                              void* d_out, int out_size, void* d_ws, size_t ws_size,
                              hipStream_t stream) {
    (void)in_sizes; (void)n_in; (void)out_size; (void)ws_size;
    const float* input   = (const float*)d_in[0];
    const float* z       = (const float*)d_in[1];
    const float* ws1_w   = (const float*)d_in[2];
    const float* ws1_b   = (const float*)d_in[3];
    const float* conv1_w = (const float*)d_in[4];
    const float* ws2_w   = (const float*)d_in[5];
    const float* ws2_b   = (const float*)d_in[6];
    const float* conv2_w = (const float*)d_in[7];
    const float* sc_w    = (const float*)d_in[8];
    // d_in[9] = sc_b: cancels exactly under training-mode BN
    const float* bn_gamma = (const float*)d_in[10];
    const float* bn_beta  = (const float*)d_in[11];

    char* ws = (char*)d_ws;
    float* y1    = (float*)(ws + OFF_Y1);
    float* y2    = (float*)(ws + OFF_Y2);
    float* stats = (float*)(ws + OFF_STATS);
    float* sbuck = (float*)(ws + OFF_SBUCK);
    u16* w1h = (u16*)(ws + OFF_W1H);
    u16* w1l = (u16*)(ws + OFF_W1L);
    u16* w2h = (u16*)(ws + OFF_W2H);
    u16* w2l = (u16*)(ws + OFF_W2L);
    u16* wsh = (u16*)(ws + OFF_WSH);
    u16* wsl = (u16*)(ws + OFF_WSL);
    u16* upH = (u16*)(ws + OFF_PLANES);
    u16* o1H = (u16*)(ws + OFF_PLANES + PLANE);
    float* tmp2 = (float*)(ws + OFF_PLANES);   // conv2 fp32 out (64MB) aliases upH (dead after sc)
    float* outp = (float*)d_out;

    hipMemsetAsync(sbuck, 0, 128 * 64 * sizeof(float), stream);
    style_y_kernel<<<4, 256, 0, stream>>>(z, ws1_w, ws1_b, ws2_w, ws2_b, y1, y2);
    modulate_kernel<<<800, 64, 0, stream>>>(conv1_w, conv2_w, sc_w, y1, y2, w1h, w1l, w2h, w2l, wsh, wsl);

    upsample_nhwc_kernel<<<2048, 256, 0, stream>>>(input, upH);

    // conv1: up -> o1H (NHWC bf16), mish, per-batch weights. 4(ct)x64(rt)x4(og)x8(b)=8192 blocks
    conv_mfma16_kernel<2, true, true, true, false><<<8192, 256, 0, stream>>>(
        upH, w1h, w1l, nullptr, o1H, nullptr);
    // shortcut: up -> d_out (fp32 NCHW), BN stats into sliced buckets. 4x64x2x8=4096 blocks
    conv_mfma16_kernel<1, false, false, false, true><<<4096, 256, 0, stream>>>(
        upH, wsh, wsl, outp, nullptr, sbuck);
    // conv2: o1H -> tmp2 (fp32 NCHW, aliases upH), mish. 4096 blocks
    conv_mfma16_kernel<1, true, true, false, false><<<4096, 256, 0, stream>>>(
        o1H, w2h, w2l, tmp2, nullptr, nullptr);

    // fold buckets, then out = conv2 + gamma_hat * sc + beta_hat (in place on d_out)
    stats_reduce_kernel<<<1, 64, 0, stream>>>(sbuck, stats);
    final_kernel<<<2048, 256, 0, stream>>>(outp, tmp2, stats, bn_gamma, bn_beta);
}